// Round 2
// baseline (543.682 us; speedup 1.0000x reference)
//
#include <hip/hip_runtime.h>
#include <hip/hip_bf16.h>
#include <stdint.h>

#define N_TOT    131072
#define DIM      256
#define KCODES   1024
#define THW      16384        // 16*32*32
#define OUT_ELEMS 33554432ULL // 8*256*16*32*32

typedef short short8 __attribute__((ext_vector_type(8)));
typedef float f32x4  __attribute__((ext_vector_type(4)));

__device__ __forceinline__ unsigned short f2bf_rne(float f) {
  union { float f; unsigned int u; } c; c.f = f;
  unsigned int u = c.u;
  unsigned int r = u + 0x7FFFu + ((u >> 16) & 1u);
  return (unsigned short)(r >> 16);
}

// ---------------- prep: embB (bf16, row stride 256), e2, zero loss ----------------
__global__ __launch_bounds__(64) void k_prep(const float* __restrict__ emb,
                                             unsigned short* __restrict__ embB,
                                             float* __restrict__ e2,
                                             float* __restrict__ lossAcc) {
  const int k = blockIdx.x;
  const int t = threadIdx.x;
  const float4 v = ((const float4*)(emb + (size_t)k * DIM))[t];   // c = 4t..4t+3
  float s = v.x * v.x + v.y * v.y + v.z * v.z + v.w * v.w;
  ushort4 bv;
  bv.x = f2bf_rne(v.x); bv.y = f2bf_rne(v.y);
  bv.z = f2bf_rne(v.z); bv.w = f2bf_rne(v.w);
  ((ushort4*)(embB + (size_t)k * DIM))[t] = bv;
  #pragma unroll
  for (int m = 32; m; m >>= 1) s += __shfl_xor(s, m, 64);
  if (t == 0) e2[k] = s;
  if (k == 0 && t == 0) *lossAcc = 0.0f;
}

// ---------------- main: fused distance-GEMM + argmin + loss partials ----------------
// 512 blocks x 256 thr. Wave = 64 rows (4 A-frags in registers). B fragments are
// loaded straight from L2-resident embB (512 KB) — no LDS, no __syncthreads.
__global__ __launch_bounds__(256, 2) void k_gemm_argmin(
    const float* __restrict__ x, const unsigned short* __restrict__ embB,
    const float* __restrict__ e2, int* __restrict__ idxOut,
    float* __restrict__ lossAcc) {
  const int tid  = threadIdx.x;
  const int wave = tid >> 6;
  const int lane = tid & 63;
  const int q    = lane >> 4;     // quad 0..3
  const int l15  = lane & 15;
  const int nw0  = blockIdx.x * 256 + wave * 64;   // wave's first row
  const int b    = nw0 >> 14;                      // batch idx (uniform: 16384 % 256 == 0)

  // ---- A fragments: 64 rows x 256 c, bf16(-2x), register-resident (128 VGPR) ----
  // A-operand layout (verified R1): lane holds A[m = l15][k = q*8 + j], j=0..7.
  short8 A[4][8];
  float x2sum = 0.0f;
  #pragma unroll
  for (int mf = 0; mf < 4; ++mf) {
    const int n   = nw0 + mf * 16 + l15;
    const int thw = n & (THW - 1);
    const float* __restrict__ xr = x + (size_t)b * DIM * THW + thw;
    #pragma unroll
    for (int ks = 0; ks < 8; ++ks) {
      const int c0 = ks * 32 + q * 8;
      short8 a;
      #pragma unroll
      for (int j = 0; j < 8; ++j) {
        float v = xr[(size_t)(c0 + j) * THW];
        x2sum += v * v;
        a[j] = (short)f2bf_rne(-2.0f * v);
      }
      A[mf][ks] = a;
    }
  }

  float mins[4][4];
  int   mini[4][4];
  #pragma unroll
  for (int mf = 0; mf < 4; ++mf)
    #pragma unroll
    for (int r = 0; r < 4; ++r) { mins[mf][r] = 3.4e38f; mini[mf][r] = 0; }

  // ---- stream codebook from L2 in 16-codeword groups; MFMA; running argmin ----
  for (int cg = 0; cg < 64; ++cg) {
    const int cod = (cg << 4) + l15;
    // B-operand (verified R1): lane holds B[k = q*8 + j][n = l15] = E[cod][c = q*8 + j]
    const unsigned short* __restrict__ br = embB + (size_t)cod * DIM + q * 8;
    short8 B[8];
    #pragma unroll
    for (int ks = 0; ks < 8; ++ks) B[ks] = *(const short8*)(br + ks * 32);
    const float e2v = e2[cod];

    f32x4 acc[4];
    #pragma unroll
    for (int mf = 0; mf < 4; ++mf) acc[mf] = (f32x4){0.f, 0.f, 0.f, 0.f};
    #pragma unroll
    for (int ks = 0; ks < 8; ++ks) {
      #pragma unroll
      for (int mf = 0; mf < 4; ++mf)
        acc[mf] = __builtin_amdgcn_mfma_f32_16x16x32_bf16(A[mf][ks], B[ks], acc[mf], 0, 0, 0);
    }
    // D layout (verified R1): row = q*4 + r, col = l15 (codeword)
    #pragma unroll
    for (int mf = 0; mf < 4; ++mf)
      #pragma unroll
      for (int r = 0; r < 4; ++r) {
        float s = acc[mf][r] + e2v;
        if (s < mins[mf][r]) { mins[mf][r] = s; mini[mf][r] = cod; }
      }
  }

  // ---- reduce argmin across the 16 lanes (cols) holding the same rows ----
  #pragma unroll
  for (int m = 1; m <= 8; m <<= 1) {
    #pragma unroll
    for (int mf = 0; mf < 4; ++mf)
      #pragma unroll
      for (int r = 0; r < 4; ++r) {
        float os = __shfl_xor(mins[mf][r], m, 64);
        int   oi = __shfl_xor(mini[mf][r], m, 64);
        if (os < mins[mf][r] || (os == mins[mf][r] && oi < mini[mf][r])) {
          mins[mf][r] = os; mini[mf][r] = oi;
        }
      }
  }

  float sstar = 0.0f;
  if (l15 == 0) {
    #pragma unroll
    for (int mf = 0; mf < 4; ++mf)
      #pragma unroll
      for (int r = 0; r < 4; ++r) {
        idxOut[nw0 + mf * 16 + q * 4 + r] = mini[mf][r];
        sstar += mins[mf][r];
      }
  }
  // loss partial: wave sum of ||x||^2 (all lanes) + s* (l15==0 lanes)
  float tot = x2sum + sstar;
  #pragma unroll
  for (int m = 32; m; m >>= 1) tot += __shfl_xor(tot, m, 64);
  if (lane == 0) atomicAdd(lossAcc, tot);
}

// ---------------- epilogue: gather + LDS transpose + coalesced store ----------------
// 2048 blocks x 256 thr; block = 64 rows x 256 c. emb rows gathered coalesced
// (1 float4/lane/row, L2-resident), transposed through stride-260 LDS tile,
// written as 256 B contiguous segments. HBM-write-bound by design.
#define TSTR 260   // floats per tile row: 16B-aligned, diagonal-conflict-free reads
__global__ __launch_bounds__(256) void k_out(
    const float* __restrict__ emb, const int* __restrict__ idx,
    float* __restrict__ out, const float* __restrict__ lossAcc) {
  __shared__ __align__(16) float tile[64 * TSTR];   // 66560 B
  __shared__ int ids[64];
  const int tid  = threadIdx.x;
  const int wave = tid >> 6;
  const int lane = tid & 63;
  const int n0   = blockIdx.x * 64;

  if (blockIdx.x == 0 && tid == 0)
    out[OUT_ELEMS] = 1.25f * lossAcc[0] * (1.0f / (float)OUT_ELEMS);

  if (tid < 64) ids[tid] = idx[n0 + tid];
  __syncthreads();

  // stage: wave w loads rows w*16 .. w*16+15 (1 KB each, one float4 per lane)
  #pragma unroll
  for (int r = 0; r < 16; ++r) {
    const int row = wave * 16 + r;
    const int id  = ids[row];                      // LDS broadcast
    const float4 v = *(const float4*)(emb + (size_t)id * DIM + lane * 4);
    *(float4*)&tile[row * TSTR + lane * 4] = v;
  }
  __syncthreads();

  // write: wave w handles c in [w*64, w*64+64); lane i holds row n0+i
  const int b    = n0 >> 14;
  const int thw0 = n0 & (THW - 1);
  float* __restrict__ ob = out + (size_t)b * DIM * THW + thw0;
  const int c0 = wave * 64;
  #pragma unroll
  for (int cc = 0; cc < 64; cc += 4) {
    const int c = c0 + cc;
    const float4 v = *(const float4*)&tile[lane * TSTR + c];
    ob[(size_t)(c + 0) * THW + lane] = v.x;
    ob[(size_t)(c + 1) * THW + lane] = v.y;
    ob[(size_t)(c + 2) * THW + lane] = v.z;
    ob[(size_t)(c + 3) * THW + lane] = v.w;
  }
}

extern "C" void kernel_launch(void* const* d_in, const int* in_sizes, int n_in,
                              void* d_out, int out_size, void* d_ws, size_t ws_size,
                              hipStream_t stream) {
  const float* x   = (const float*)d_in[0];
  const float* emb = (const float*)d_in[1];
  float* out = (float*)d_out;
  char* ws = (char*)d_ws;

  // workspace layout (16B aligned), total ~1.03 MB
  unsigned short* embB = (unsigned short*)(ws);          // 1024*256*2 = 524288 B
  float* e2      = (float*)(ws + 524288);                // 4096 B
  int*   idx     = (int*)(ws + 528384);                  // 131072*4 = 524288 B
  float* lossAcc = (float*)(ws + 1052672);               // 4 B

  k_prep<<<KCODES, 64, 0, stream>>>(emb, embB, e2, lossAcc);
  k_gemm_argmin<<<N_TOT / 256, 256, 0, stream>>>(x, embB, e2, idx, lossAcc);
  k_out<<<N_TOT / 64, 256, 0, stream>>>(emb, idx, out, lossAcc);
}

// Round 3
// 364.444 us; speedup vs baseline: 1.4918x; 1.4918x over previous
//
#include <hip/hip_runtime.h>
#include <hip/hip_bf16.h>
#include <stdint.h>

#define N_TOT    131072
#define DIM      256
#define KCODES   1024
#define THW      16384        // 16*32*32
#define OUT_ELEMS 33554432ULL // 8*256*16*32*32

typedef short short8 __attribute__((ext_vector_type(8)));
typedef float f32x4  __attribute__((ext_vector_type(4)));

__device__ __forceinline__ unsigned short f2bf_rne(float f) {
  union { float f; unsigned int u; } c; c.f = f;
  unsigned int u = c.u;
  unsigned int r = u + 0x7FFFu + ((u >> 16) & 1u);
  return (unsigned short)(r >> 16);
}

__device__ __forceinline__ void async_cp16(void* lds, const void* gsrc) {
  __builtin_amdgcn_global_load_lds(
      (const __attribute__((address_space(1))) void*)gsrc,
      (__attribute__((address_space(3))) void*)lds, 16, 0, 0);
}

// ---------------- prep: embB in MFMA B-FRAGMENT ORDER (bf16), e2, zero loss ----------
// Fragment order: for codeword k, channel c:
//   cg = k>>4, l15 = k&15, ks = c>>5, q = (c>>3)&3, j = c&7, lane = q*16+l15
//   ushort index = ((cg*8 + ks)*64 + lane)*8 + j
// => a wave's ds_read_b128 at ((cg*8+ks)*64 + lane)*16 B is LINEAR (0 conflicts),
//    and global->LDS staging is a straight linear memcpy.
__global__ __launch_bounds__(64) void k_prep(const float* __restrict__ emb,
                                             unsigned short* __restrict__ embB,
                                             float* __restrict__ e2,
                                             float* __restrict__ lossAcc) {
  const int k = blockIdx.x;
  const int t = threadIdx.x;
  const float4 v = ((const float4*)(emb + (size_t)k * DIM))[t];   // c = 4t..4t+3
  float s = v.x * v.x + v.y * v.y + v.z * v.z + v.w * v.w;
  ushort4 bv;
  bv.x = f2bf_rne(v.x); bv.y = f2bf_rne(v.y);
  bv.z = f2bf_rne(v.z); bv.w = f2bf_rne(v.w);
  const int c0 = 4 * t;
  const int ks = c0 >> 5, q = (c0 >> 3) & 3, j0 = c0 & 7;
  const int lane = q * 16 + (k & 15);
  unsigned short* dst = embB + (size_t)((((k >> 4) * 8 + ks) * 64 + lane) * 8 + j0);
  *(ushort4*)dst = bv;
  #pragma unroll
  for (int m = 32; m; m >>= 1) s += __shfl_xor(s, m, 64);
  if (t == 0) e2[k] = s;
  if (k == 0 && t == 0) *lossAcc = 0.0f;
}

// ---------------- main: fused distance-GEMM + argmin + loss partials ----------------
// 1024 blocks x 256 thr (4 waves x 32 rows). A register-resident (2 frags, 64 VGPR).
// Codebook streamed through LDS: 16 chunks of 64 codewords (32 KB), double-buffered,
// ONE barrier per chunk; staging is linear global_load_lds dwordx4.
__global__ __launch_bounds__(256) void k_gemm_argmin(
    const float* __restrict__ x, const unsigned short* __restrict__ embB,
    const float* __restrict__ e2, int* __restrict__ idxOut,
    float* __restrict__ lossAcc) {
  __shared__ __align__(16) unsigned short eT[2][16384];   // 2 x 32 KB

  const int tid  = threadIdx.x;
  const int wave = tid >> 6;
  const int lane = tid & 63;
  const int q    = lane >> 4;     // quad 0..3
  const int l15  = lane & 15;
  const int nw0  = blockIdx.x * 128 + wave * 32;   // wave's first row
  const int b    = nw0 >> 14;                      // batch idx (uniform: 16384 % 128 == 0)

  // ---- stage chunk 0 while we build A ----
  {
    const char* gsrc = (const char*)embB;
    char* ldst = (char*)&eT[0][0];
    #pragma unroll
    for (int kk = 0; kk < 8; ++kk)
      async_cp16(ldst + (tid + kk * 256) * 16, gsrc + (size_t)(tid + kk * 256) * 16);
  }

  // ---- A fragments: 32 rows x 256 c, bf16(-2x), register-resident (64 VGPR) ----
  // A-operand layout (verified R1): lane holds A[m = l15][k = q*8 + j], j=0..7.
  short8 A[2][8];
  float x2sum = 0.0f;
  #pragma unroll
  for (int mf = 0; mf < 2; ++mf) {
    const int n   = nw0 + mf * 16 + l15;
    const int thw = n & (THW - 1);
    const float* __restrict__ xr = x + (size_t)b * DIM * THW + thw;
    #pragma unroll
    for (int ks = 0; ks < 8; ++ks) {
      const int c0 = ks * 32 + q * 8;
      short8 a;
      #pragma unroll
      for (int j = 0; j < 8; ++j) {
        float v = xr[(size_t)(c0 + j) * THW];
        x2sum += v * v;
        a[j] = (short)f2bf_rne(-2.0f * v);
      }
      A[mf][ks] = a;
    }
  }

  float mins[2][4];
  int   mini[2][4];
  #pragma unroll
  for (int mf = 0; mf < 2; ++mf)
    #pragma unroll
    for (int r = 0; r < 4; ++r) { mins[mf][r] = 3.4e38f; mini[mf][r] = 0; }

  __syncthreads();   // chunk 0 staged

  // ---- 16 chunks x 64 codewords; prefetch next, consume current, 1 barrier ----
  for (int ch = 0; ch < 16; ++ch) {
    if (ch + 1 < 16) {
      const char* gsrc = (const char*)embB + (size_t)(ch + 1) * 32768;
      char* ldst = (char*)&eT[(ch + 1) & 1][0];
      #pragma unroll
      for (int kk = 0; kk < 8; ++kk)
        async_cp16(ldst + (tid + kk * 256) * 16, gsrc + (size_t)(tid + kk * 256) * 16);
    }
    const unsigned short* __restrict__ buf = &eT[ch & 1][0];
    const int cb = ch * 64;

    #pragma unroll
    for (int cgl = 0; cgl < 4; ++cgl) {
      // B-operand: lane holds B[k = q*8+j][n = l15]; fragment-order => linear reads
      short8 B[8];
      #pragma unroll
      for (int ks = 0; ks < 8; ++ks)
        B[ks] = *(const short8*)(buf + (size_t)(((cgl * 8 + ks) * 64 + lane) * 8));
      const int   cod = cb + cgl * 16 + l15;
      const float e2v = e2[cod];

      f32x4 acc0 = {0.f, 0.f, 0.f, 0.f};
      f32x4 acc1 = {0.f, 0.f, 0.f, 0.f};
      #pragma unroll
      for (int ks = 0; ks < 8; ++ks) {
        acc0 = __builtin_amdgcn_mfma_f32_16x16x32_bf16(A[0][ks], B[ks], acc0, 0, 0, 0);
        acc1 = __builtin_amdgcn_mfma_f32_16x16x32_bf16(A[1][ks], B[ks], acc1, 0, 0, 0);
      }
      // D layout (verified R1): row = q*4 + r, col = l15 (codeword)
      #pragma unroll
      for (int r = 0; r < 4; ++r) {
        float s0 = acc0[r] + e2v;
        if (s0 < mins[0][r]) { mins[0][r] = s0; mini[0][r] = cod; }
        float s1 = acc1[r] + e2v;
        if (s1 < mins[1][r]) { mins[1][r] = s1; mini[1][r] = cod; }
      }
    }
    __syncthreads();   // prefetch landed (it flew over ~64 MFMAs) + buf-reuse guard
  }

  // ---- reduce argmin across the 16 lanes (cols) holding the same rows ----
  #pragma unroll
  for (int m = 1; m <= 8; m <<= 1) {
    #pragma unroll
    for (int mf = 0; mf < 2; ++mf)
      #pragma unroll
      for (int r = 0; r < 4; ++r) {
        float os = __shfl_xor(mins[mf][r], m, 64);
        int   oi = __shfl_xor(mini[mf][r], m, 64);
        if (os < mins[mf][r] || (os == mins[mf][r] && oi < mini[mf][r])) {
          mins[mf][r] = os; mini[mf][r] = oi;
        }
      }
  }

  float sstar = 0.0f;
  if (l15 == 0) {
    #pragma unroll
    for (int mf = 0; mf < 2; ++mf)
      #pragma unroll
      for (int r = 0; r < 4; ++r) {
        idxOut[nw0 + mf * 16 + q * 4 + r] = mini[mf][r];
        sstar += mins[mf][r];
      }
  }
  float tot = x2sum + sstar;
  #pragma unroll
  for (int m = 32; m; m >>= 1) tot += __shfl_xor(tot, m, 64);
  if (lane == 0) atomicAdd(lossAcc, tot);
}

// ---------------- epilogue: gather + LDS transpose + float4 coalesced stores --------
// 512 blocks x 256 thr; block = 256 rows x 256 c, c in 4 chunks of 64.
// tile[n][c] stride 65 floats: gather writes (b128) and transpose reads are <=2-way.
// Stores are 16 B/lane, 1 KB/wave-inst, fully coalesced. HBM-write-bound by design.
#define TSTR 65
__global__ __launch_bounds__(256) void k_out(
    const float* __restrict__ emb, const int* __restrict__ idx,
    float* __restrict__ out, const float* __restrict__ lossAcc) {
  __shared__ __align__(16) float tile[256 * TSTR];   // 66560 B
  const int tid  = threadIdx.x;
  const int wave = tid >> 6;
  const int lane = tid & 63;
  const int l15  = lane & 15;
  const int n0   = blockIdx.x * 256;

  if (blockIdx.x == 0 && tid == 0)
    out[OUT_ELEMS] = 1.25f * lossAcc[0] * (1.0f / (float)OUT_ELEMS);

  const int myid = idx[n0 + tid];                  // this thread's row id
  const int b    = n0 >> 14;                       // uniform (16384 % 256 == 0)
  const int thw0 = n0 & (THW - 1);
  float* __restrict__ ob = out + (size_t)b * DIM * THW + thw0;
  const float* __restrict__ er = emb + (size_t)myid * DIM;

  for (int cc = 0; cc < 4; ++cc) {
    const int c0 = cc * 64;
    // gather: thread t fills tile row t with emb[myid][c0..c0+63]
    #pragma unroll
    for (int j = 0; j < 16; ++j) {
      const float4 v = *(const float4*)(er + c0 + 4 * j);
      *(float4*)&tile[tid * TSTR + 4 * j] = v;
    }
    __syncthreads();
    // store: wave w covers n = w*64 .. w*64+63; lane: n = w*64 + 4*l15, c = c0+(l>>4)+4*ci
    #pragma unroll
    for (int ci = 0; ci < 16; ++ci) {
      const int dc = (lane >> 4) + 4 * ci;
      const int nl = wave * 64 + 4 * l15;
      float4 v;
      v.x = tile[(nl + 0) * TSTR + dc];
      v.y = tile[(nl + 1) * TSTR + dc];
      v.z = tile[(nl + 2) * TSTR + dc];
      v.w = tile[(nl + 3) * TSTR + dc];
      *(float4*)(ob + (size_t)(c0 + dc) * THW + nl) = v;
    }
    __syncthreads();   // before next chunk's gather overwrites tile
  }
}

extern "C" void kernel_launch(void* const* d_in, const int* in_sizes, int n_in,
                              void* d_out, int out_size, void* d_ws, size_t ws_size,
                              hipStream_t stream) {
  const float* x   = (const float*)d_in[0];
  const float* emb = (const float*)d_in[1];
  float* out = (float*)d_out;
  char* ws = (char*)d_ws;

  // workspace layout (16B aligned), total ~1.03 MB
  unsigned short* embB = (unsigned short*)(ws);          // 1024*256*2 = 524288 B (frag order)
  float* e2      = (float*)(ws + 524288);                // 4096 B
  int*   idx     = (int*)(ws + 528384);                  // 131072*4 = 524288 B
  float* lossAcc = (float*)(ws + 1052672);               // 4 B

  k_prep<<<KCODES, 64, 0, stream>>>(emb, embB, e2, lossAcc);
  k_gemm_argmin<<<N_TOT / 128, 256, 0, stream>>>(x, embB, e2, idx, lossAcc);
  k_out<<<N_TOT / 256, 256, 0, stream>>>(emb, idx, out, lossAcc);
}